// Round 3
// baseline (405.410 us; speedup 1.0000x reference)
//
#include <hip/hip_runtime.h>
#include <math.h>

typedef unsigned short u16;
typedef __bf16 bf16x8 __attribute__((ext_vector_type(8)));
typedef float f32x4 __attribute__((ext_vector_type(4)));
typedef short s16x8 __attribute__((ext_vector_type(8)));
typedef short s16x4 __attribute__((ext_vector_type(4)));

__device__ __forceinline__ float b2f(u16 u) {
    union { unsigned i; float f; } c; c.i = ((unsigned)u) << 16; return c.f;
}
__device__ __forceinline__ u16 f2b(float f) {
    union { float f; unsigned i; } c; c.f = f;
    return (u16)((c.i + 0x7fffu + ((c.i >> 16) & 1u)) >> 16);
}
__device__ __forceinline__ float gelu_f(float v) {
    return 0.5f * v * (1.0f + erff(v * 0.70710678118654752f));
}
__device__ __forceinline__ void async_cp16(const u16* g, u16* l) {
    __builtin_amdgcn_global_load_lds((const __attribute__((address_space(1))) void*)g,
                                     (__attribute__((address_space(3))) void*)l, 16, 0, 0);
}

#define BK 64

// C[m][colh] = sum_k A[m][k]*W[colh][k] + bias[colh]; all A/W bf16, bias f32.
// Two halves (half = bx >= halfBlocks) with separate A/W/bias/out/mode/ldo.
// Each block computes 128 rows x (128*SUBN) cols. mode 0: bf16 out; 1: f32 sigmoid.
template<int SUBN>
__global__ __launch_bounds__(256, 2)
void gemm_bt(const u16* __restrict__ A0, const u16* __restrict__ A1,
             const u16* __restrict__ W0, const u16* __restrict__ W1,
             const float* __restrict__ B0, const float* __restrict__ B1,
             void* __restrict__ O0v, void* __restrict__ O1v,
             int lda, int K, int halfBlocks, int ldo0, int ldo1,
             int mode0, int mode1)
{
    __shared__ u16 sA[128 * BK];
    __shared__ u16 sW[SUBN * 128 * BK];

    const int bx = blockIdx.x, by = blockIdx.y;
    const int half = (bx >= halfBlocks) ? 1 : 0;
    const int bxl = bx - half * halfBlocks;
    const u16* A = (half ? A1 : A0) + (size_t)by * 128 * lda;
    const u16* W = (half ? W1 : W0) + (size_t)bxl * (128 * SUBN) * K;
    const float* bias = half ? B1 : B0;
    void* outv = half ? O1v : O0v;
    const int ldo = half ? ldo1 : ldo0;
    const int mode = half ? mode1 : mode0;

    const int tid = threadIdx.x;
    const int lane = tid & 63;
    const int wave = tid >> 6;
    const int wm = (wave >> 1) * 64;
    const int wn = (wave & 1) * 64;
    const int fc = lane & 15;
    const int quad = lane >> 4;

    // chunk slot p (16B) holds row r=p>>3, logical k8-chunk c8=((p&7)-(r&7))&7;
    // i.e. physical slot for (r,c8) is r*8 + ((c8 + r)&7) -> bank-spread frag reads.
    int pr[4], pc[4];
#pragma unroll
    for (int c = 0; c < 4; ++c) {
        const int p = tid + 256 * c;
        pr[c] = p >> 3;
        pc[c] = ((p & 7) - (pr[c] & 7)) & 7;
    }

    f32x4 acc[4][4 * SUBN];
#pragma unroll
    for (int i = 0; i < 4; ++i)
#pragma unroll
        for (int j = 0; j < 4 * SUBN; ++j)
            acc[i][j] = f32x4{0.f, 0.f, 0.f, 0.f};

    for (int k0 = 0; k0 < K; k0 += BK) {
#pragma unroll
        for (int c = 0; c < 4; ++c)
            async_cp16(A + (size_t)pr[c] * lda + k0 + pc[c] * 8, &sA[(tid + 256 * c) * 8]);
#pragma unroll
        for (int sub = 0; sub < SUBN; ++sub)
#pragma unroll
            for (int c = 0; c < 4; ++c)
                async_cp16(W + (size_t)(sub * 128 + pr[c]) * K + k0 + pc[c] * 8,
                           &sW[(sub * 1024 + tid + 256 * c) * 8]);
        __syncthreads();

#pragma unroll
        for (int kk = 0; kk < 2; ++kk) {
            bf16x8 af[4];
#pragma unroll
            for (int i = 0; i < 4; ++i) {
                const int ar = wm + i * 16 + fc;
                const int slot = ar * 8 + ((kk * 4 + quad + (ar & 7)) & 7);
                af[i] = *(const bf16x8*)&sA[slot * 8];
            }
#pragma unroll
            for (int sub = 0; sub < SUBN; ++sub) {
                bf16x8 wf[4];
#pragma unroll
                for (int j = 0; j < 4; ++j) {
                    const int wr = wn + j * 16 + fc;
                    const int slot = sub * 1024 + wr * 8 + ((kk * 4 + quad + (wr & 7)) & 7);
                    wf[j] = *(const bf16x8*)&sW[slot * 8];
                }
#pragma unroll
                for (int i = 0; i < 4; ++i)
#pragma unroll
                    for (int j = 0; j < 4; ++j)
                        acc[i][sub * 4 + j] =
                            __builtin_amdgcn_mfma_f32_16x16x32_bf16(af[i], wf[j], acc[i][sub * 4 + j], 0, 0, 0);
            }
        }
        __syncthreads();
    }

#pragma unroll
    for (int sub = 0; sub < SUBN; ++sub) {
#pragma unroll
        for (int j = 0; j < 4; ++j) {
            const int colh = bxl * (128 * SUBN) + sub * 128 + wn + j * 16 + fc;
            const float bv = bias[colh];
#pragma unroll
            for (int i = 0; i < 4; ++i) {
#pragma unroll
                for (int r = 0; r < 4; ++r) {
                    const int row = by * 128 + wm + i * 16 + quad * 4 + r;
                    const float v = acc[i][sub * 4 + j][r] + bv;
                    if (mode == 1)
                        ((float*)outv)[(size_t)row * ldo + colh] = 1.0f / (1.0f + expf(-v));
                    else
                        ((u16*)outv)[(size_t)row * ldo + colh] = f2b(v);
                }
            }
        }
    }
}

// ---- prep helpers -------------------------------------------------------

// NN f32 GEMM 64x64 tile: C = A[M,K] @ B[K,N]; out f32 (Cf) or bf16 (Cb), ld=ldc.
__device__ void sgemm_nn(const float* __restrict__ A, int lda,
                         const float* __restrict__ Bm, int ldb, int K,
                         int bi, int bj, float* sA, float* sB,
                         float* Cf, u16* Cb, int ldc, int tid)
{
    const int ty = tid >> 4, tx = tid & 15;
    float acc[4][4];
#pragma unroll
    for (int i = 0; i < 4; ++i)
#pragma unroll
        for (int j = 0; j < 4; ++j) acc[i][j] = 0.f;

    for (int kt = 0; kt < K; kt += 16) {
        {
            const int r = tid >> 2, c = (tid & 3) * 4;
            *(f32x4*)&sA[r * 16 + c] = *(const f32x4*)&A[(size_t)(bi * 64 + r) * lda + kt + c];
        }
        {
            const int r = tid >> 4, c = (tid & 15) * 4;
            *(f32x4*)&sB[r * 64 + c] = *(const f32x4*)&Bm[(size_t)(kt + r) * ldb + bj * 64 + c];
        }
        __syncthreads();
#pragma unroll 4
        for (int k = 0; k < 16; ++k) {
            float a[4], b[4];
#pragma unroll
            for (int i = 0; i < 4; ++i) a[i] = sA[(ty * 4 + i) * 16 + k];
#pragma unroll
            for (int j = 0; j < 4; ++j) b[j] = sB[k * 64 + tx * 4 + j];
#pragma unroll
            for (int i = 0; i < 4; ++i)
#pragma unroll
                for (int j = 0; j < 4; ++j) acc[i][j] += a[i] * b[j];
        }
        __syncthreads();
    }
#pragma unroll
    for (int i = 0; i < 4; ++i)
#pragma unroll
        for (int j = 0; j < 4; ++j) {
            const int row = bi * 64 + ty * 4 + i, col = bj * 64 + tx * 4 + j;
            if (Cb) Cb[(size_t)row * ldc + col] = f2b(acc[i][j]);
            else Cf[(size_t)row * ldc + col] = acc[i][j];
        }
}

// out[i] = M[i,:]@v + (add1?add1[i]:0) + (add2?add2[i]:0), M [512x512]
__device__ void matvec512(const float* __restrict__ M, const float* __restrict__ v,
                          const float* add1, const float* add2,
                          float* __restrict__ out, float* sv, int tid)
{
    for (int i = tid; i < 512; i += 256) sv[i] = v[i];
    __syncthreads();
#pragma unroll
    for (int rr = 0; rr < 2; ++rr) {
        const int i = rr * 256 + tid;
        float s = 0.f;
        for (int k = 0; k < 512; k += 4) {
            f32x4 m = *(const f32x4*)&M[(size_t)i * 512 + k];
            s += m[0] * sv[k] + m[1] * sv[k + 1] + m[2] * sv[k + 2] + m[3] * sv[k + 3];
        }
        out[i] = s + (add1 ? add1[i] : 0.f) + (add2 ? add2[i] : 0.f);
    }
}

__device__ __forceinline__ void cvt_quads(const float* __restrict__ src,
                                          u16* __restrict__ dst, int bi, int tid)
{
#pragma unroll
    for (int c = 0; c < 2; ++c) {
        const int q = bi * 512 + tid + 256 * c;
        f32x4 v = *(const f32x4*)(src + (size_t)q * 4);
        s16x4 o;
        o[0] = (short)f2b(v[0]); o[1] = (short)f2b(v[1]);
        o[2] = (short)f2b(v[2]); o[3] = (short)f2b(v[3]);
        *(s16x4*)(dst + (size_t)q * 4) = o;
    }
}

// P1: EMB cvt, weight cvts, U1 = a1_wv@tp_w, U2 = a2_wv@np_w, u1/u2 matvecs
__global__ __launch_bounds__(256)
void prep1(const float* __restrict__ text, const float* __restrict__ num,
           const float* __restrict__ tp_w, const float* __restrict__ np_w,
           const float* __restrict__ g_w, const float* __restrict__ m1_w,
           const float* __restrict__ m2_w,
           const float* __restrict__ a1_wv, const float* __restrict__ a2_wv,
           const float* __restrict__ tp_b, const float* __restrict__ np_b,
           const float* __restrict__ a1_bv, const float* __restrict__ a2_bv,
           u16* __restrict__ EMBc, u16* __restrict__ Wbig,
           u16* __restrict__ g_bf, u16* __restrict__ m1_bf, u16* __restrict__ m2_bf,
           float* __restrict__ U1, float* __restrict__ U2,
           float* __restrict__ u1, float* __restrict__ u2)
{
    __shared__ float smem[64 * 16 + 16 * 64];
    const int b = blockIdx.x, tid = threadIdx.x;
    if (b < 4096) {                       // EMBc[row, 0:256]=text, [256:512]=num (bf16)
#pragma unroll
        for (int c = 0; c < 2; ++c) {
            const int q = b * 512 + tid + 256 * c;
            const int e = q * 4, row = e >> 9, col = e & 511;
            const float* src = (col < 256) ? text + (size_t)row * 256 + col
                                           : num + (size_t)row * 256 + (col - 256);
            f32x4 v = *(const f32x4*)src;
            s16x4 o;
            o[0] = (short)f2b(v[0]); o[1] = (short)f2b(v[1]);
            o[2] = (short)f2b(v[2]); o[3] = (short)f2b(v[3]);
            *(s16x4*)(EMBc + e) = o;
        }
    } else if (b < 4352) { cvt_quads(g_w, g_bf, b - 4096, tid); }
    else if (b < 4608) { cvt_quads(m1_w, m1_bf, b - 4352, tid); }
    else if (b < 4672) { cvt_quads(m2_w, m2_bf, b - 4608, tid); }
    else if (b < 4736) {                  // np_w -> Wbig[0:512, 256:512]
#pragma unroll
        for (int c = 0; c < 2; ++c) {
            const int q = (b - 4672) * 512 + tid + 256 * c;
            const int e = q * 4, row = e >> 8, col = e & 255;
            f32x4 v = *(const f32x4*)(np_w + e);
            s16x4 o;
            o[0] = (short)f2b(v[0]); o[1] = (short)f2b(v[1]);
            o[2] = (short)f2b(v[2]); o[3] = (short)f2b(v[3]);
            *(s16x4*)(Wbig + (size_t)row * 512 + 256 + col) = o;
        }
    } else if (b < 4800) {                // tp_w -> Wbig[512:1024, 0:256]
#pragma unroll
        for (int c = 0; c < 2; ++c) {
            const int q = (b - 4736) * 512 + tid + 256 * c;
            const int e = q * 4, row = e >> 8, col = e & 255;
            f32x4 v = *(const f32x4*)(tp_w + e);
            s16x4 o;
            o[0] = (short)f2b(v[0]); o[1] = (short)f2b(v[1]);
            o[2] = (short)f2b(v[2]); o[3] = (short)f2b(v[3]);
            *(s16x4*)(Wbig + (size_t)(512 + row) * 512 + col) = o;
        }
    } else if (b < 4832) {
        const int t = b - 4800;
        sgemm_nn(a1_wv, 512, tp_w, 256, 512, t >> 2, t & 3, smem, smem + 64 * 16,
                 U1, nullptr, 256, tid);
    } else if (b < 4864) {
        const int t = b - 4832;
        sgemm_nn(a2_wv, 512, np_w, 256, 512, t >> 2, t & 3, smem, smem + 64 * 16,
                 U2, nullptr, 256, tid);
    } else if (b == 4864) { matvec512(a1_wv, tp_b, a1_bv, nullptr, u1, smem, tid); }
    else { matvec512(a2_wv, np_b, a2_bv, nullptr, u2, smem, tid); }
}

// P2: A1L = a1_wo@U1 -> Wbig[0:512,0:256]; A2R = a2_wo@U2 -> Wbig[512:,256:];
//     bL = np_b + a1_wo@u1 + a1_bo; bR = tp_b + a2_wo@u2 + a2_bo
__global__ __launch_bounds__(256)
void prep2(const float* __restrict__ a1_wo, const float* __restrict__ a2_wo,
           const float* __restrict__ U1, const float* __restrict__ U2,
           const float* __restrict__ u1, const float* __restrict__ u2,
           const float* __restrict__ np_b, const float* __restrict__ a1_bo,
           const float* __restrict__ tp_b, const float* __restrict__ a2_bo,
           u16* __restrict__ Wbig, float* __restrict__ bbig)
{
    __shared__ float smem[64 * 16 + 16 * 64];
    const int b = blockIdx.x, tid = threadIdx.x;
    if (b < 32) {
        sgemm_nn(a1_wo, 512, U1, 256, 512, b >> 2, b & 3, smem, smem + 64 * 16,
                 nullptr, Wbig, 512, tid);
    } else if (b < 64) {
        const int t = b - 32;
        sgemm_nn(a2_wo, 512, U2, 256, 512, t >> 2, t & 3, smem, smem + 64 * 16,
                 nullptr, Wbig + (size_t)512 * 512 + 256, 512, tid);
    } else if (b == 64) { matvec512(a1_wo, u1, np_b, a1_bo, bbig, smem, tid); }
    else { matvec512(a2_wo, u2, tp_b, a2_bo, bbig + 512, smem, tid); }
}

// ---- LN kernels ---------------------------------------------------------

// in-place LN over X [B,1024]: cols 0:512 with n1 (y_L), 512:1024 with n2 (y_R)
__global__ __launch_bounds__(256)
void ln_inplace(u16* __restrict__ X,
                const float* __restrict__ g1, const float* __restrict__ b1,
                const float* __restrict__ g2, const float* __restrict__ b2)
{
    const int w = blockIdx.x * 4 + (threadIdx.x >> 6);
    const int lane = threadIdx.x & 63;
    const int row = w >> 1, half = w & 1;
    u16* p = X + (size_t)row * 1024 + half * 512;
    const float* g = half ? g2 : g1;
    const float* b = half ? b2 : b1;
    const int c = lane * 8;
    s16x8 xv = *(const s16x8*)(p + c);
    float x[8], s = 0.f, ss = 0.f;
#pragma unroll
    for (int j = 0; j < 8; ++j) { x[j] = b2f((u16)xv[j]); s += x[j]; ss += x[j] * x[j]; }
#pragma unroll
    for (int m = 32; m >= 1; m >>= 1) { s += __shfl_xor(s, m, 64); ss += __shfl_xor(ss, m, 64); }
    const float mean = s * (1.f / 512.f);
    const float var = ss * (1.f / 512.f) - mean * mean;
    const float rs = rsqrtf(var + 1e-5f);
    s16x8 y;
#pragma unroll
    for (int j = 0; j < 8; ++j)
        y[j] = (short)f2b((x[j] - mean) * rs * g[c + j] + b[c + j]);
    *(s16x8*)(p + c) = y;
}

__global__ __launch_bounds__(256)
void ln_gelu512(const u16* __restrict__ X, const float* __restrict__ g,
                const float* __restrict__ b, u16* __restrict__ out)
{
    const int row = blockIdx.x * 4 + (threadIdx.x >> 6);
    const int lane = threadIdx.x & 63;
    const int c = lane * 8;
    s16x8 xv = *(const s16x8*)(X + (size_t)row * 512 + c);
    float x[8], s = 0.f, ss = 0.f;
#pragma unroll
    for (int j = 0; j < 8; ++j) { x[j] = b2f((u16)xv[j]); s += x[j]; ss += x[j] * x[j]; }
#pragma unroll
    for (int m = 32; m >= 1; m >>= 1) { s += __shfl_xor(s, m, 64); ss += __shfl_xor(ss, m, 64); }
    const float mean = s * (1.f / 512.f);
    const float var = ss * (1.f / 512.f) - mean * mean;
    const float rs = rsqrtf(var + 1e-5f);
    s16x8 y;
#pragma unroll
    for (int j = 0; j < 8; ++j)
        y[j] = (short)f2b(gelu_f((x[j] - mean) * rs * g[c + j] + b[c + j]));
    *(s16x8*)(out + (size_t)row * 512 + c) = y;
}

__global__ __launch_bounds__(256)
void ln_gelu256_out(const u16* __restrict__ Z, const float* __restrict__ g,
                    const float* __restrict__ b, float* __restrict__ dout)
{
    const int row = blockIdx.x * 4 + (threadIdx.x >> 6);
    const int lane = threadIdx.x & 63;
    const int c = lane * 4;
    s16x4 xv = *(const s16x4*)(Z + (size_t)row * 256 + c);
    float x[4], s = 0.f, ss = 0.f;
#pragma unroll
    for (int j = 0; j < 4; ++j) { x[j] = b2f((u16)xv[j]); s += x[j]; ss += x[j] * x[j]; }
#pragma unroll
    for (int m = 32; m >= 1; m >>= 1) { s += __shfl_xor(s, m, 64); ss += __shfl_xor(ss, m, 64); }
    const float mean = s * (1.f / 256.f);
    const float var = ss * (1.f / 256.f) - mean * mean;
    const float rs = rsqrtf(var + 1e-5f);
    f32x4 y;
#pragma unroll
    for (int j = 0; j < 4; ++j)
        y[j] = gelu_f((x[j] - mean) * rs * g[c + j] + b[c + j]);
    *(f32x4*)(dout + (size_t)row * 256 + c) = y;
    if (lane == 0) {
        dout[(size_t)16384 * 768 + row] = 1.0f;   // attn_n2t
        dout[(size_t)16384 * 769 + row] = 1.0f;   // attn_t2n
    }
}

extern "C" void kernel_launch(void* const* d_in, const int* in_sizes, int n_in,
                              void* d_out, int out_size, void* d_ws, size_t ws_size,
                              hipStream_t stream)
{
    const float* text  = (const float*)d_in[0];
    const float* num   = (const float*)d_in[1];
    const float* tp_w  = (const float*)d_in[2];
    const float* tp_b  = (const float*)d_in[3];
    const float* np_w  = (const float*)d_in[4];
    const float* np_b  = (const float*)d_in[5];
    const float* a1_wv = (const float*)d_in[8];
    const float* a1_bv = (const float*)d_in[11];
    const float* a1_wo = (const float*)d_in[12];
    const float* a1_bo = (const float*)d_in[13];
    const float* a2_wv = (const float*)d_in[16];
    const float* a2_bv = (const float*)d_in[19];
    const float* a2_wo = (const float*)d_in[20];
    const float* a2_bo = (const float*)d_in[21];
    const float* n1_g  = (const float*)d_in[22];
    const float* n1_b  = (const float*)d_in[23];
    const float* n2_g  = (const float*)d_in[24];
    const float* n2_b  = (const float*)d_in[25];
    const float* g_b   = (const float*)d_in[27];
    const float* g_w   = (const float*)d_in[26];
    const float* m1_w  = (const float*)d_in[28];
    const float* m1_b  = (const float*)d_in[29];
    const float* ln1_g = (const float*)d_in[30];
    const float* ln1_b = (const float*)d_in[31];
    const float* m2_w  = (const float*)d_in[32];
    const float* m2_b  = (const float*)d_in[33];
    const float* ln2_g = (const float*)d_in[34];
    const float* ln2_b = (const float*)d_in[35];

    float* outp = (float*)d_out;
    char* ob = (char*)d_out;
    char* ws = (char*)d_ws;
    const size_t MB = 1048576;

    // d_out scratch (fused region [0,16MB) dead until L3; gate region [16,48MB) dead until G2)
    u16* Wbig  = (u16*)ob;                          // 1 MB  [1024 x 512] bf16
    u16* g_bf  = (u16*)(ob + 1 * MB);               // 1 MB  [512 x 1024]
    u16* m1_bf = (u16*)(ob + 2 * MB);               // 1 MB  [512 x 1024]
    u16* m2_bf = (u16*)(ob + 3 * MB);               // 256 KB [256 x 512]
    float* U1  = (float*)(ob + 3 * MB + 512 * 1024);// 512 KB [512 x 256] f32
    float* U2  = (float*)(ob + 4 * MB);             // 512 KB
    float* u1v = (float*)(ob + 4 * MB + 512 * 1024);
    float* u2v = u1v + 512;
    float* bbig = u1v + 1024;                       // [1024] f32
    u16* EMBc  = (u16*)(ob + 16 * MB);              // 16 MB [16384 x 512] bf16
    // ws (64 MB)
    u16* X  = (u16*)ws;                             // 32 MB [16384 x 1024]; comb in-place
    u16* Y2 = (u16*)(ws + 32 * MB);                 // 16 MB [16384 x 512]
    u16* h  = (u16*)(ws + 48 * MB);                 // 16 MB [16384 x 512]
    u16* Z  = (u16*)ws;                             // 8 MB [16384 x 256]; comb dead after G2

    dim3 blk(256);

    prep1<<<4866, blk, 0, stream>>>(text, num, tp_w, np_w, g_w, m1_w, m2_w,
        a1_wv, a2_wv, tp_b, np_b, a1_bv, a2_bv,
        EMBc, Wbig, g_bf, m1_bf, m2_bf, U1, U2, u1v, u2v);
    prep2<<<66, blk, 0, stream>>>(a1_wo, a2_wo, U1, U2, u1v, u2v,
        np_b, a1_bo, tp_b, a2_bo, Wbig, bbig);
    // G1: X = [text|num] @ Wbig.T + bbig   (y_L | y_R, pre-LN, residuals folded)
    gemm_bt<2><<<dim3(4, 128), blk, 0, stream>>>(EMBc, EMBc,
        Wbig, Wbig + (size_t)512 * 512, bbig, bbig + 512,
        X, X + 512, 512, 512, 2, 1024, 1024, 0, 0);
    // L1: comb = LN(X) in place (left: n1, right: n2)
    ln_inplace<<<8192, blk, 0, stream>>>(X, n1_g, n1_b, n2_g, n2_b);
    // G2: gate = sigmoid(comb@g_w.T+g_b) -> d_out f32 ; Y2 = comb@m1_w.T+m1_b bf16
    gemm_bt<2><<<dim3(4, 128), blk, 0, stream>>>(X, X, g_bf, m1_bf, g_b, m1_b,
        outp + (size_t)16384 * 256, Y2, 1024, 1024, 2, 512, 512, 1, 0);
    // L2: h = gelu(LN(Y2))
    ln_gelu512<<<4096, blk, 0, stream>>>(Y2, ln1_g, ln1_b, h);
    // G3: Z = h @ m2_w.T + m2_b
    gemm_bt<1><<<dim3(2, 128), blk, 0, stream>>>(h, h,
        m2_bf, m2_bf + (size_t)128 * 512, m2_b, m2_b + 128,
        Z, Z + 128, 512, 512, 1, 256, 256, 0, 0);
    // L3: fused = gelu(LN(Z)) -> d_out; attn = 1.0
    ln_gelu256_out<<<4096, blk, 0, stream>>>(Z, ln2_g, ln2_b, outp);
}

// Round 4
// 360.585 us; speedup vs baseline: 1.1243x; 1.1243x over previous
//
#include <hip/hip_runtime.h>
#include <math.h>

typedef unsigned short u16;
typedef __bf16 bf16x8 __attribute__((ext_vector_type(8)));
typedef float f32x4 __attribute__((ext_vector_type(4)));
typedef short s16x8 __attribute__((ext_vector_type(8)));
typedef short s16x4 __attribute__((ext_vector_type(4)));

__device__ __forceinline__ float b2f(u16 u) {
    union { unsigned i; float f; } c; c.i = ((unsigned)u) << 16; return c.f;
}
__device__ __forceinline__ u16 f2b(float f) {
    union { float f; unsigned i; } c; c.f = f;
    return (u16)((c.i + 0x7fffu + ((c.i >> 16) & 1u)) >> 16);
}
__device__ __forceinline__ float gelu_f(float v) {
    return 0.5f * v * (1.0f + erff(v * 0.70710678118654752f));
}
__device__ __forceinline__ void async_cp16(const u16* g, u16* l) {
    __builtin_amdgcn_global_load_lds((const __attribute__((address_space(1))) void*)g,
                                     (__attribute__((address_space(3))) void*)l, 16, 0, 0);
}

#define BK 64

// C[m][colh] = sum_k A[m][k]*W[colh][k] + bias[colh]; all A/W bf16, bias f32.
// Two halves (half = bx >= halfBlocks) with separate A/W/bias/out/mode/ldo.
// Each block computes 128 rows x (128*SUBN) cols. mode 0: bf16 out; 1: f32 sigmoid.
template<int SUBN>
__global__ __launch_bounds__(256, 2)
void gemm_bt(const u16* __restrict__ A0, const u16* __restrict__ A1,
             const u16* __restrict__ W0, const u16* __restrict__ W1,
             const float* __restrict__ B0, const float* __restrict__ B1,
             void* __restrict__ O0v, void* __restrict__ O1v,
             int lda, int K, int halfBlocks, int ldo0, int ldo1,
             int mode0, int mode1)
{
    __shared__ u16 sA[128 * BK];
    __shared__ u16 sW[SUBN * 128 * BK];

    const int bx = blockIdx.x, by = blockIdx.y;
    const int half = (bx >= halfBlocks) ? 1 : 0;
    const int bxl = bx - half * halfBlocks;
    const u16* A = (half ? A1 : A0) + (size_t)by * 128 * lda;
    const u16* W = (half ? W1 : W0) + (size_t)bxl * (128 * SUBN) * K;
    const float* bias = half ? B1 : B0;
    void* outv = half ? O1v : O0v;
    const int ldo = half ? ldo1 : ldo0;
    const int mode = half ? mode1 : mode0;

    const int tid = threadIdx.x;
    const int lane = tid & 63;
    const int wave = tid >> 6;
    const int wm = (wave >> 1) * 64;
    const int wn = (wave & 1) * 64;
    const int fc = lane & 15;
    const int quad = lane >> 4;

    // chunk slot p (16B) holds row r=p>>3, logical k8-chunk c8=((p&7)-(r&7))&7;
    // i.e. physical slot for (r,c8) is r*8 + ((c8 + r)&7) -> bank-spread frag reads.
    int pr[4], pc[4];
#pragma unroll
    for (int c = 0; c < 4; ++c) {
        const int p = tid + 256 * c;
        pr[c] = p >> 3;
        pc[c] = ((p & 7) - (pr[c] & 7)) & 7;
    }

    f32x4 acc[4][4 * SUBN];
#pragma unroll
    for (int i = 0; i < 4; ++i)
#pragma unroll
        for (int j = 0; j < 4 * SUBN; ++j)
            acc[i][j] = f32x4{0.f, 0.f, 0.f, 0.f};

    for (int k0 = 0; k0 < K; k0 += BK) {
#pragma unroll
        for (int c = 0; c < 4; ++c)
            async_cp16(A + (size_t)pr[c] * lda + k0 + pc[c] * 8, &sA[(tid + 256 * c) * 8]);
#pragma unroll
        for (int sub = 0; sub < SUBN; ++sub)
#pragma unroll
            for (int c = 0; c < 4; ++c)
                async_cp16(W + (size_t)(sub * 128 + pr[c]) * K + k0 + pc[c] * 8,
                           &sW[(sub * 1024 + tid + 256 * c) * 8]);
        __syncthreads();

#pragma unroll
        for (int kk = 0; kk < 2; ++kk) {
            bf16x8 af[4];
#pragma unroll
            for (int i = 0; i < 4; ++i) {
                const int ar = wm + i * 16 + fc;
                const int slot = ar * 8 + ((kk * 4 + quad + (ar & 7)) & 7);
                af[i] = *(const bf16x8*)&sA[slot * 8];
            }
#pragma unroll
            for (int sub = 0; sub < SUBN; ++sub) {
                bf16x8 wf[4];
#pragma unroll
                for (int j = 0; j < 4; ++j) {
                    const int wr = wn + j * 16 + fc;
                    const int slot = sub * 1024 + wr * 8 + ((kk * 4 + quad + (wr & 7)) & 7);
                    wf[j] = *(const bf16x8*)&sW[slot * 8];
                }
#pragma unroll
                for (int i = 0; i < 4; ++i)
#pragma unroll
                    for (int j = 0; j < 4; ++j)
                        acc[i][sub * 4 + j] =
                            __builtin_amdgcn_mfma_f32_16x16x32_bf16(af[i], wf[j], acc[i][sub * 4 + j], 0, 0, 0);
            }
        }
        __syncthreads();
    }

#pragma unroll
    for (int sub = 0; sub < SUBN; ++sub) {
#pragma unroll
        for (int j = 0; j < 4; ++j) {
            const int colh = bxl * (128 * SUBN) + sub * 128 + wn + j * 16 + fc;
            const float bv = bias[colh];
#pragma unroll
            for (int i = 0; i < 4; ++i) {
#pragma unroll
                for (int r = 0; r < 4; ++r) {
                    const int row = by * 128 + wm + i * 16 + quad * 4 + r;
                    const float v = acc[i][sub * 4 + j][r] + bv;
                    if (mode == 1)
                        ((float*)outv)[(size_t)row * ldo + colh] = 1.0f / (1.0f + expf(-v));
                    else
                        ((u16*)outv)[(size_t)row * ldo + colh] = f2b(v);
                }
            }
        }
    }
}

// ---- prep ---------------------------------------------------------------

__device__ __forceinline__ void cvt_quads(const float* __restrict__ src,
                                          u16* __restrict__ dst, int bi, int tid)
{
#pragma unroll
    for (int c = 0; c < 2; ++c) {
        const int q = bi * 512 + tid + 256 * c;
        f32x4 v = *(const f32x4*)(src + (size_t)q * 4);
        s16x4 o;
        o[0] = (short)f2b(v[0]); o[1] = (short)f2b(v[1]);
        o[2] = (short)f2b(v[2]); o[3] = (short)f2b(v[3]);
        *(s16x4*)(dst + (size_t)q * 4) = o;
    }
}

// one 64x64 tile transpose+cvt: dst[(tc+j)*R + tr+i] = src[(tr+i)*C + tc+j]
__device__ void transpose_cvt64(const float* __restrict__ src, int C,
                                u16* __restrict__ dst, int R,
                                int tr, int tc, int tid, float* sm)
{
    const int lr = tid >> 4, lc4 = (tid & 15) * 4;
#pragma unroll
    for (int m = 0; m < 4; ++m) {
        const int i = lr + m * 16;
        f32x4 v = *(const f32x4*)&src[(size_t)(tr + i) * C + tc + lc4];
#pragma unroll
        for (int mm = 0; mm < 4; ++mm) sm[i * 65 + lc4 + mm] = v[mm];
    }
    __syncthreads();
#pragma unroll
    for (int m = 0; m < 4; ++m) {
        const int j = lr + m * 16;
        s16x4 o;
#pragma unroll
        for (int mm = 0; mm < 4; ++mm)
            o[mm] = (short)f2b(sm[(size_t)(lc4 + mm) * 65 + j]);
        *(s16x4*)&dst[(size_t)(tc + j) * R + tr + lc4] = o;
    }
}

// wv[i] = sum_k M[i][k]*v[k] + add1[i] + add2[i]  (M f32 [512x512]); 64 rows/block
__device__ void matvec_rows(const float* __restrict__ M, const float* __restrict__ v,
                            const float* __restrict__ add1, const float* __restrict__ add2,
                            float* __restrict__ out, int r0, int tid, float* sm)
{
    for (int i = tid; i < 512; i += 256) sm[i] = v[i];
    __syncthreads();
    const int row = r0 + (tid & 63), q = tid >> 6;
    float s = 0.f;
    for (int k = q * 128; k < q * 128 + 128; k += 4) {
        f32x4 m = *(const f32x4*)&M[(size_t)row * 512 + k];
        s += m[0] * sm[k] + m[1] * sm[k + 1] + m[2] * sm[k + 2] + m[3] * sm[k + 3];
    }
    sm[512 + tid] = s;
    __syncthreads();
    if (tid < 64)
        out[r0 + tid] = sm[512 + tid] + sm[512 + tid + 64] + sm[512 + tid + 128] +
                        sm[512 + tid + 192] + add1[r0 + tid] + add2[r0 + tid];
}

// prep_cvt: EMB cvt, weight cvts, transposes, w1/w2, zbias. All memory-bound.
__global__ __launch_bounds__(256)
void prep_cvt(const float* __restrict__ text, const float* __restrict__ num,
              const float* __restrict__ tp_w, const float* __restrict__ np_w,
              const float* __restrict__ g_w, const float* __restrict__ m1_w,
              const float* __restrict__ m2_w,
              const float* __restrict__ a1_wv, const float* __restrict__ a2_wv,
              const float* __restrict__ a1_wo, const float* __restrict__ a2_wo,
              const float* __restrict__ a1_bv, const float* __restrict__ a1_bo,
              const float* __restrict__ a2_bv, const float* __restrict__ a2_bo,
              const float* __restrict__ tp_b, const float* __restrict__ np_b,
              u16* __restrict__ EMBc, u16* __restrict__ Wbig,
              u16* __restrict__ g_bf, u16* __restrict__ m1_bf, u16* __restrict__ m2_bf,
              u16* __restrict__ a1_wvT, u16* __restrict__ a2_wvT,
              u16* __restrict__ tp_wT, u16* __restrict__ np_wT,
              u16* __restrict__ a1_wo_bf, u16* __restrict__ a2_wo_bf,
              float* __restrict__ w1, float* __restrict__ w2,
              float* __restrict__ zb)
{
    __shared__ float smem[64 * 65];
    const int b = blockIdx.x, tid = threadIdx.x;
    if (b < 4096) {                       // EMBc[row,0:256]=text, [256:512]=num
#pragma unroll
        for (int c = 0; c < 2; ++c) {
            const int q = b * 512 + tid + 256 * c;
            const int e = q * 4, row = e >> 9, col = e & 511;
            const float* src = (col < 256) ? text + (size_t)row * 256 + col
                                           : num + (size_t)row * 256 + (col - 256);
            f32x4 v = *(const f32x4*)src;
            s16x4 o;
            o[0] = (short)f2b(v[0]); o[1] = (short)f2b(v[1]);
            o[2] = (short)f2b(v[2]); o[3] = (short)f2b(v[3]);
            *(s16x4*)(EMBc + e) = o;
        }
    } else if (b < 4352) { cvt_quads(g_w, g_bf, b - 4096, tid); }
    else if (b < 4608) { cvt_quads(m1_w, m1_bf, b - 4352, tid); }
    else if (b < 4672) { cvt_quads(m2_w, m2_bf, b - 4608, tid); }
    else if (b < 4736) {                  // np_w -> Wbig[0:512, 256:512]
#pragma unroll
        for (int c = 0; c < 2; ++c) {
            const int q = (b - 4672) * 512 + tid + 256 * c;
            const int e = q * 4, row = e >> 8, col = e & 255;
            f32x4 v = *(const f32x4*)(np_w + e);
            s16x4 o;
            o[0] = (short)f2b(v[0]); o[1] = (short)f2b(v[1]);
            o[2] = (short)f2b(v[2]); o[3] = (short)f2b(v[3]);
            *(s16x4*)(Wbig + (size_t)row * 512 + 256 + col) = o;
        }
    } else if (b < 4800) {                // tp_w -> Wbig[512:1024, 0:256]
#pragma unroll
        for (int c = 0; c < 2; ++c) {
            const int q = (b - 4736) * 512 + tid + 256 * c;
            const int e = q * 4, row = e >> 8, col = e & 255;
            f32x4 v = *(const f32x4*)(tp_w + e);
            s16x4 o;
            o[0] = (short)f2b(v[0]); o[1] = (short)f2b(v[1]);
            o[2] = (short)f2b(v[2]); o[3] = (short)f2b(v[3]);
            *(s16x4*)(Wbig + (size_t)(512 + row) * 512 + col) = o;
        }
    } else if (b < 4864) {                // a1_wvT = a1_wv.T (bf16)
        const int t = b - 4800;
        transpose_cvt64(a1_wv, 512, a1_wvT, 512, (t >> 3) * 64, (t & 7) * 64, tid, smem);
    } else if (b < 4928) {
        const int t = b - 4864;
        transpose_cvt64(a2_wv, 512, a2_wvT, 512, (t >> 3) * 64, (t & 7) * 64, tid, smem);
    } else if (b < 4960) {                // tp_wT [256x512]
        const int t = b - 4928;
        transpose_cvt64(tp_w, 256, tp_wT, 512, (t >> 2) * 64, (t & 3) * 64, tid, smem);
    } else if (b < 4992) {                // np_wT [256x512]
        const int t = b - 4960;
        transpose_cvt64(np_w, 256, np_wT, 512, (t >> 2) * 64, (t & 3) * 64, tid, smem);
    } else if (b < 5120) { cvt_quads(a1_wo, a1_wo_bf, b - 4992, tid); }
    else if (b < 5248) { cvt_quads(a2_wo, a2_wo_bf, b - 5120, tid); }
    else if (b < 5256) {                  // w1 = a1_wo@a1_bv + a1_bo + np_b
        matvec_rows(a1_wo, a1_bv, a1_bo, np_b, w1, (b - 5248) * 64, tid, smem);
    } else if (b < 5264) {                // w2 = a2_wo@a2_bv + a2_bo + tp_b
        matvec_rows(a2_wo, a2_bv, a2_bo, tp_b, w2, (b - 5256) * 64, tid, smem);
    } else {                              // zb[1024] = 0
        *(f32x4*)&zb[tid * 4] = f32x4{0.f, 0.f, 0.f, 0.f};
    }
}

// bbig[0:512] = M1@tp_b + w1 ; bbig[512:1024] = M2@np_b + w2. M bf16 [512x512].
__global__ __launch_bounds__(256)
void prep_bias(const u16* __restrict__ M1, const u16* __restrict__ M2,
               const float* __restrict__ tp_b, const float* __restrict__ np_b,
               const float* __restrict__ w1, const float* __restrict__ w2,
               float* __restrict__ bbig)
{
    __shared__ float sm[768];
    const int b = blockIdx.x, tid = threadIdx.x;
    const int side = b >> 3, r0 = (b & 7) * 64;
    const u16* M = side ? M2 : M1;
    const float* v = side ? np_b : tp_b;
    const float* w = side ? w2 : w1;
    float* out = bbig + side * 512;
    for (int i = tid; i < 512; i += 256) sm[i] = v[i];
    __syncthreads();
    const int row = r0 + (tid & 63), q = tid >> 6;
    float s = 0.f;
    for (int k = q * 128; k < q * 128 + 128; k += 8) {
        s16x8 m = *(const s16x8*)&M[(size_t)row * 512 + k];
#pragma unroll
        for (int j = 0; j < 8; ++j) s += b2f((u16)m[j]) * sm[k + j];
    }
    sm[512 + tid] = s;
    __syncthreads();
    if (tid < 64)
        out[r0 + tid] = sm[512 + tid] + sm[512 + tid + 64] + sm[512 + tid + 128] +
                        sm[512 + tid + 192] + w[r0 + tid];
}

// ---- LN kernels ---------------------------------------------------------

__global__ __launch_bounds__(256)
void ln_inplace(u16* __restrict__ X,
                const float* __restrict__ g1, const float* __restrict__ b1,
                const float* __restrict__ g2, const float* __restrict__ b2)
{
    const int w = blockIdx.x * 4 + (threadIdx.x >> 6);
    const int lane = threadIdx.x & 63;
    const int row = w >> 1, half = w & 1;
    u16* p = X + (size_t)row * 1024 + half * 512;
    const float* g = half ? g2 : g1;
    const float* b = half ? b2 : b1;
    const int c = lane * 8;
    s16x8 xv = *(const s16x8*)(p + c);
    float x[8], s = 0.f, ss = 0.f;
#pragma unroll
    for (int j = 0; j < 8; ++j) { x[j] = b2f((u16)xv[j]); s += x[j]; ss += x[j] * x[j]; }
#pragma unroll
    for (int m = 32; m >= 1; m >>= 1) { s += __shfl_xor(s, m, 64); ss += __shfl_xor(ss, m, 64); }
    const float mean = s * (1.f / 512.f);
    const float var = ss * (1.f / 512.f) - mean * mean;
    const float rs = rsqrtf(var + 1e-5f);
    s16x8 y;
#pragma unroll
    for (int j = 0; j < 8; ++j)
        y[j] = (short)f2b((x[j] - mean) * rs * g[c + j] + b[c + j]);
    *(s16x8*)(p + c) = y;
}

__global__ __launch_bounds__(256)
void ln_gelu512(const u16* __restrict__ X, const float* __restrict__ g,
                const float* __restrict__ b, u16* __restrict__ out)
{
    const int row = blockIdx.x * 4 + (threadIdx.x >> 6);
    const int lane = threadIdx.x & 63;
    const int c = lane * 8;
    s16x8 xv = *(const s16x8*)(X + (size_t)row * 512 + c);
    float x[8], s = 0.f, ss = 0.f;
#pragma unroll
    for (int j = 0; j < 8; ++j) { x[j] = b2f((u16)xv[j]); s += x[j]; ss += x[j] * x[j]; }
#pragma unroll
    for (int m = 32; m >= 1; m >>= 1) { s += __shfl_xor(s, m, 64); ss += __shfl_xor(ss, m, 64); }
    const float mean = s * (1.f / 512.f);
    const float var = ss * (1.f / 512.f) - mean * mean;
    const float rs = rsqrtf(var + 1e-5f);
    s16x8 y;
#pragma unroll
    for (int j = 0; j < 8; ++j)
        y[j] = (short)f2b(gelu_f((x[j] - mean) * rs * g[c + j] + b[c + j]));
    *(s16x8*)(out + (size_t)row * 512 + c) = y;
}

__global__ __launch_bounds__(256)
void ln_gelu256_out(const u16* __restrict__ Z, const float* __restrict__ g,
                    const float* __restrict__ b, float* __restrict__ dout)
{
    const int row = blockIdx.x * 4 + (threadIdx.x >> 6);
    const int lane = threadIdx.x & 63;
    const int c = lane * 4;
    s16x4 xv = *(const s16x4*)(Z + (size_t)row * 256 + c);
    float x[4], s = 0.f, ss = 0.f;
#pragma unroll
    for (int j = 0; j < 4; ++j) { x[j] = b2f((u16)xv[j]); s += x[j]; ss += x[j] * x[j]; }
#pragma unroll
    for (int m = 32; m >= 1; m >>= 1) { s += __shfl_xor(s, m, 64); ss += __shfl_xor(ss, m, 64); }
    const float mean = s * (1.f / 256.f);
    const float var = ss * (1.f / 256.f) - mean * mean;
    const float rs = rsqrtf(var + 1e-5f);
    f32x4 y;
#pragma unroll
    for (int j = 0; j < 4; ++j)
        y[j] = gelu_f((x[j] - mean) * rs * g[c + j] + b[c + j]);
    *(f32x4*)(dout + (size_t)row * 256 + c) = y;
    if (lane == 0) {
        dout[(size_t)16384 * 768 + row] = 1.0f;   // attn_n2t
        dout[(size_t)16384 * 769 + row] = 1.0f;   // attn_t2n
    }
}

extern "C" void kernel_launch(void* const* d_in, const int* in_sizes, int n_in,
                              void* d_out, int out_size, void* d_ws, size_t ws_size,
                              hipStream_t stream)
{
    const float* text  = (const float*)d_in[0];
    const float* num   = (const float*)d_in[1];
    const float* tp_w  = (const float*)d_in[2];
    const float* tp_b  = (const float*)d_in[3];
    const float* np_w  = (const float*)d_in[4];
    const float* np_b  = (const float*)d_in[5];
    const float* a1_wv = (const float*)d_in[8];
    const float* a1_bv = (const float*)d_in[11];
    const float* a1_wo = (const float*)d_in[12];
    const float* a1_bo = (const float*)d_in[13];
    const float* a2_wv = (const float*)d_in[16];
    const float* a2_bv = (const float*)d_in[19];
    const float* a2_wo = (const float*)d_in[20];
    const float* a2_bo = (const float*)d_in[21];
    const float* n1_g  = (const float*)d_in[22];
    const float* n1_b  = (const float*)d_in[23];
    const float* n2_g  = (const float*)d_in[24];
    const float* n2_b  = (const float*)d_in[25];
    const float* g_w   = (const float*)d_in[26];
    const float* g_b   = (const float*)d_in[27];
    const float* m1_w  = (const float*)d_in[28];
    const float* m1_b  = (const float*)d_in[29];
    const float* ln1_g = (const float*)d_in[30];
    const float* ln1_b = (const float*)d_in[31];
    const float* m2_w  = (const float*)d_in[32];
    const float* m2_b  = (const float*)d_in[33];
    const float* ln2_g = (const float*)d_in[34];
    const float* ln2_b = (const float*)d_in[35];

    float* outp = (float*)d_out;
    char* ob = (char*)d_out;
    char* ws = (char*)d_ws;
    const size_t KB = 1024, MB = 1048576;

    // d_out scratch: [0,16MB) dead until L3 (weights); [16,48MB) dead until G2 (EMBc)
    u16* Wbig    = (u16*)(ob);                       // 1 MB   [1024x512]
    u16* g_bf    = (u16*)(ob + 1 * MB);              // 1 MB   [512x1024]
    u16* m1_bf   = (u16*)(ob + 2 * MB);              // 1 MB   [512x1024]
    u16* m2_bf   = (u16*)(ob + 3 * MB);              // 256 KB [256x512]
    u16* a1_wvT  = (u16*)(ob + 3 * MB + 256 * KB);   // 512 KB [512x512]
    u16* a2_wvT  = (u16*)(ob + 3 * MB + 768 * KB);   // 512 KB
    u16* tp_wT   = (u16*)(ob + 4 * MB + 256 * KB);   // 256 KB [256x512]
    u16* np_wT   = (u16*)(ob + 4 * MB + 512 * KB);   // 256 KB
    u16* a1_wo_bf= (u16*)(ob + 4 * MB + 768 * KB);   // 512 KB [512x512]
    u16* a2_wo_bf= (u16*)(ob + 5 * MB + 256 * KB);   // 512 KB
    u16* M1      = (u16*)(ob + 5 * MB + 768 * KB);   // 512 KB [512x512]
    u16* M2      = (u16*)(ob + 6 * MB + 256 * KB);   // 512 KB
    float* w1    = (float*)(ob + 6 * MB + 768 * KB); // 2 KB
    float* w2    = w1 + 512;                         // 2 KB
    float* bbig  = w1 + 1024;                        // 4 KB
    float* zb    = w1 + 2048;                        // 4 KB
    u16* EMBc    = (u16*)(ob + 16 * MB);             // 16 MB [16384x512]
    // ws
    u16* X  = (u16*)ws;                              // 32 MB [16384x1024]
    u16* Y2 = (u16*)(ws + 32 * MB);                  // 16 MB [16384x512]
    u16* h  = (u16*)(ws + 48 * MB);                  // 16 MB [16384x512]
    u16* Z  = (u16*)ws;                              // 8 MB  [16384x256] (X dead after G2)

    dim3 blk(256);

    // P1: conversions, transposes, w1/w2, zbias
    prep_cvt<<<5265, blk, 0, stream>>>(text, num, tp_w, np_w, g_w, m1_w, m2_w,
        a1_wv, a2_wv, a1_wo, a2_wo, a1_bv, a1_bo, a2_bv, a2_bo, tp_b, np_b,
        EMBc, Wbig, g_bf, m1_bf, m2_bf, a1_wvT, a2_wvT, tp_wT, np_wT,
        a1_wo_bf, a2_wo_bf, w1, w2, zb);
    // F1: M1 = a1_wo@a1_wv ; M2 = a2_wo@a2_wv   (MFMA, bf16 out)
    gemm_bt<2><<<dim3(4, 4), blk, 0, stream>>>(a1_wo_bf, a2_wo_bf, a1_wvT, a2_wvT,
        zb, zb, M1, M2, 512, 512, 2, 512, 512, 0, 0);
    // PB: bbig = [M1@tp_b + w1 | M2@np_b + w2]
    prep_bias<<<16, blk, 0, stream>>>(M1, M2, tp_b, np_b, w1, w2, bbig);
    // F2: Wbig[0:512,0:256] = M1@tp_w ; Wbig[512:,256:] = M2@np_w
    gemm_bt<2><<<dim3(2, 4), blk, 0, stream>>>(M1, M2, tp_wT, np_wT,
        zb, zb, Wbig, Wbig + (size_t)512 * 512 + 256, 512, 512, 1, 512, 512, 0, 0);
    // G1: X = EMBc @ Wbig.T + bbig  (y_L | y_R, residuals folded)
    gemm_bt<2><<<dim3(4, 128), blk, 0, stream>>>(EMBc, EMBc,
        Wbig, Wbig + (size_t)512 * 512, bbig, bbig + 512,
        X, X + 512, 512, 512, 2, 1024, 1024, 0, 0);
    // L1: comb = LN(X) in place
    ln_inplace<<<8192, blk, 0, stream>>>(X, n1_g, n1_b, n2_g, n2_b);
    // G2: gate = sigmoid(comb@g_w.T+g_b) -> d_out f32 ; Y2 = comb@m1_w.T+m1_b
    gemm_bt<2><<<dim3(4, 128), blk, 0, stream>>>(X, X, g_bf, m1_bf, g_b, m1_b,
        outp + (size_t)16384 * 256, Y2, 1024, 1024, 2, 512, 512, 1, 0);
    // L2: h = gelu(LN(Y2))
    ln_gelu512<<<4096, blk, 0, stream>>>(Y2, ln1_g, ln1_b, h);
    // G3: Z = h @ m2_w.T + m2_b
    gemm_bt<1><<<dim3(2, 128), blk, 0, stream>>>(h, h,
        m2_bf, m2_bf + (size_t)128 * 512, m2_b, m2_b + 128,
        Z, Z + 128, 512, 512, 1, 256, 256, 0, 0);
    // L3: fused = gelu(LN(Z)) -> d_out; attn = 1.0
    ln_gelu256_out<<<4096, blk, 0, stream>>>(Z, ln2_g, ln2_b, outp);
}